// Round 4
// baseline (33576.959 us; speedup 1.0000x reference)
//
#include <hip/hip_runtime.h>
#include <math.h>

// ---------------------------------------------------------------------------
// V projection precompute (fp32 SGEMM): out[b][h][m][d], row-major [m][d]
// grid: jt(8) + 8*(mt(8) + 8*b(128)); block 256 = 16x16 threads, 4x4 out each
// ---------------------------------------------------------------------------
__global__ __launch_bounds__(256) void kv_proj(
    const float* __restrict__ mem, const float* __restrict__ W,
    const float* __restrict__ bias, float* __restrict__ outp) {
  __shared__ float As[32][68];
  __shared__ float Bs[32][68];
  int gid = blockIdx.x;
  int jt = gid & 7, mt = (gid >> 3) & 7, b = gid >> 6;
  int t = threadIdx.x;
  int lm = t >> 2;
  int kq = (t & 3) * 8;
  int tx = t & 15, ty = t >> 4;
  float acc[4][4];
  #pragma unroll
  for (int r = 0; r < 4; ++r)
    #pragma unroll
    for (int c = 0; c < 4; ++c) acc[r][c] = 0.f;
  const float* Arow = mem + (size_t)(mt * 64 + lm) * 65536 + (size_t)b * 512 + kq;
  const float* Brow = W + (size_t)(jt * 64 + lm) * 512 + kq;
  for (int k0 = 0; k0 < 512; k0 += 32) {
    float4 a0 = *(const float4*)(Arow + k0);
    float4 a1 = *(const float4*)(Arow + k0 + 4);
    float4 b0 = *(const float4*)(Brow + k0);
    float4 b1 = *(const float4*)(Brow + k0 + 4);
    As[kq + 0][lm] = a0.x; As[kq + 1][lm] = a0.y; As[kq + 2][lm] = a0.z; As[kq + 3][lm] = a0.w;
    As[kq + 4][lm] = a1.x; As[kq + 5][lm] = a1.y; As[kq + 6][lm] = a1.z; As[kq + 7][lm] = a1.w;
    Bs[kq + 0][lm] = b0.x; Bs[kq + 1][lm] = b0.y; Bs[kq + 2][lm] = b0.z; Bs[kq + 3][lm] = b0.w;
    Bs[kq + 4][lm] = b1.x; Bs[kq + 5][lm] = b1.y; Bs[kq + 6][lm] = b1.z; Bs[kq + 7][lm] = b1.w;
    __syncthreads();
    #pragma unroll
    for (int k = 0; k < 32; ++k) {
      float4 av = *(const float4*)&As[k][ty * 4];
      float4 bv = *(const float4*)&Bs[k][tx * 4];
      float ar[4] = {av.x, av.y, av.z, av.w};
      float br[4] = {bv.x, bv.y, bv.z, bv.w};
      #pragma unroll
      for (int r = 0; r < 4; ++r)
        #pragma unroll
        for (int c = 0; c < 4; ++c) acc[r][c] = fmaf(ar[r], br[c], acc[r][c]);
    }
    __syncthreads();
  }
  float4 bb = *(const float4*)(bias + jt * 64 + tx * 4);
  #pragma unroll
  for (int r = 0; r < 4; ++r) {
    int m = mt * 64 + ty * 4 + r;
    float4 o;
    o.x = acc[r][0] + bb.x; o.y = acc[r][1] + bb.y;
    o.z = acc[r][2] + bb.z; o.w = acc[r][3] + bb.w;
    *(float4*)(outp + (((size_t)b * 8 + jt) * 512 + m) * 64 + tx * 4) = o;
  }
}

// ---------------------------------------------------------------------------
// K projection, TRANSPOSED output: out[b][h][d][m]  (d = head-local 0..63)
// ---------------------------------------------------------------------------
__global__ __launch_bounds__(256) void kv_projT(
    const float* __restrict__ mem, const float* __restrict__ W,
    const float* __restrict__ bias, float* __restrict__ outp) {
  __shared__ float As[32][68];
  __shared__ float Bs[32][68];
  int gid = blockIdx.x;
  int jt = gid & 7, mt = (gid >> 3) & 7, b = gid >> 6;
  int t = threadIdx.x;
  int lm = t >> 2;
  int kq = (t & 3) * 8;
  int tx = t & 15, ty = t >> 4;
  float acc[4][4];
  #pragma unroll
  for (int r = 0; r < 4; ++r)
    #pragma unroll
    for (int c = 0; c < 4; ++c) acc[r][c] = 0.f;
  const float* Arow = mem + (size_t)(mt * 64 + lm) * 65536 + (size_t)b * 512 + kq;
  const float* Brow = W + (size_t)(jt * 64 + lm) * 512 + kq;
  for (int k0 = 0; k0 < 512; k0 += 32) {
    float4 a0 = *(const float4*)(Arow + k0);
    float4 a1 = *(const float4*)(Arow + k0 + 4);
    float4 b0 = *(const float4*)(Brow + k0);
    float4 b1 = *(const float4*)(Brow + k0 + 4);
    As[kq + 0][lm] = a0.x; As[kq + 1][lm] = a0.y; As[kq + 2][lm] = a0.z; As[kq + 3][lm] = a0.w;
    As[kq + 4][lm] = a1.x; As[kq + 5][lm] = a1.y; As[kq + 6][lm] = a1.z; As[kq + 7][lm] = a1.w;
    Bs[kq + 0][lm] = b0.x; Bs[kq + 1][lm] = b0.y; Bs[kq + 2][lm] = b0.z; Bs[kq + 3][lm] = b0.w;
    Bs[kq + 4][lm] = b1.x; Bs[kq + 5][lm] = b1.y; Bs[kq + 6][lm] = b1.z; Bs[kq + 7][lm] = b1.w;
    __syncthreads();
    #pragma unroll
    for (int k = 0; k < 32; ++k) {
      float4 av = *(const float4*)&As[k][ty * 4];
      float4 bv = *(const float4*)&Bs[k][tx * 4];
      float ar[4] = {av.x, av.y, av.z, av.w};
      float br[4] = {bv.x, bv.y, bv.z, bv.w};
      #pragma unroll
      for (int r = 0; r < 4; ++r)
        #pragma unroll
        for (int c = 0; c < 4; ++c) acc[r][c] = fmaf(ar[r], br[c], acc[r][c]);
    }
    __syncthreads();
  }
  float4 bb = *(const float4*)(bias + jt * 64 + tx * 4);
  float bc[4] = {bb.x, bb.y, bb.z, bb.w};
  #pragma unroll
  for (int r = 0; r < 4; ++r) {
    int m = mt * 64 + ty * 4 + r;
    #pragma unroll
    for (int c = 0; c < 4; ++c) {
      int d = tx * 4 + c;
      outp[((size_t)(b * 8 + jt) * 64 + d) * 512 + m] = acc[r][c] + bc[c];
    }
  }
}

// ---------------------------------------------------------------------------
// emb_q precompute: emb_q[v][j] = sum_{k<512} emb[v][k] * Wq[j][k], v<1000
// grid: jt(8) + 8*vt(16) = 128 blocks
// ---------------------------------------------------------------------------
__global__ __launch_bounds__(256) void embq_proj(
    const float* __restrict__ emb, const float* __restrict__ Wq,
    float* __restrict__ outp) {
  __shared__ float As[32][68];
  __shared__ float Bs[32][68];
  int gid = blockIdx.x;
  int jt = gid & 7, vt = gid >> 3;
  int t = threadIdx.x;
  int lm = t >> 2;
  int kq = (t & 3) * 8;
  int tx = t & 15, ty = t >> 4;
  float acc[4][4];
  #pragma unroll
  for (int r = 0; r < 4; ++r)
    #pragma unroll
    for (int c = 0; c < 4; ++c) acc[r][c] = 0.f;
  int v = vt * 64 + lm;
  bool va = v < 1000;
  const float* Arow = emb + (size_t)(va ? v : 0) * 512 + kq;
  const float* Brow = Wq + (size_t)(jt * 64 + lm) * 1024 + kq;  // emb-half cols
  for (int k0 = 0; k0 < 512; k0 += 32) {
    float4 a0 = va ? *(const float4*)(Arow + k0) : make_float4(0, 0, 0, 0);
    float4 a1 = va ? *(const float4*)(Arow + k0 + 4) : make_float4(0, 0, 0, 0);
    float4 b0 = *(const float4*)(Brow + k0);
    float4 b1 = *(const float4*)(Brow + k0 + 4);
    As[kq + 0][lm] = a0.x; As[kq + 1][lm] = a0.y; As[kq + 2][lm] = a0.z; As[kq + 3][lm] = a0.w;
    As[kq + 4][lm] = a1.x; As[kq + 5][lm] = a1.y; As[kq + 6][lm] = a1.z; As[kq + 7][lm] = a1.w;
    Bs[kq + 0][lm] = b0.x; Bs[kq + 1][lm] = b0.y; Bs[kq + 2][lm] = b0.z; Bs[kq + 3][lm] = b0.w;
    Bs[kq + 4][lm] = b1.x; Bs[kq + 5][lm] = b1.y; Bs[kq + 6][lm] = b1.z; Bs[kq + 7][lm] = b1.w;
    __syncthreads();
    #pragma unroll
    for (int k = 0; k < 32; ++k) {
      float4 av = *(const float4*)&As[k][ty * 4];
      float4 bv = *(const float4*)&Bs[k][tx * 4];
      float ar[4] = {av.x, av.y, av.z, av.w};
      float br[4] = {bv.x, bv.y, bv.z, bv.w};
      #pragma unroll
      for (int r = 0; r < 4; ++r)
        #pragma unroll
        for (int c = 0; c < 4; ++c) acc[r][c] = fmaf(ar[r], br[c], acc[r][c]);
    }
    __syncthreads();
  }
  #pragma unroll
  for (int r = 0; r < 4; ++r) {
    int v2 = vt * 64 + ty * 4 + r;
    if (v2 < 1000) {
      float4 o;
      o.x = acc[r][0]; o.y = acc[r][1]; o.z = acc[r][2]; o.w = acc[r][3];
      *(float4*)(outp + (size_t)v2 * 512 + jt * 64 + tx * 4) = o;
    }
  }
}

// ---------------------------------------------------------------------------
// WqhT[k][j] = Wq[j][512+k]  (one-time, 1 MB)
// ---------------------------------------------------------------------------
__global__ __launch_bounds__(256) void wqh_transpose(
    const float* __restrict__ Wq, float* __restrict__ WqhT) {
  int idx = blockIdx.x * 256 + threadIdx.x;  // grid 1024
  int k = idx >> 9, j = idx & 511;
  WqhT[(size_t)k * 512 + j] = Wq[(size_t)j * 1024 + 512 + k];
}

// ---------------------------------------------------------------------------
__global__ __launch_bounds__(256) void init_kernel(float* __restrict__ h0,
                                                   float* __restrict__ qh,
                                                   unsigned long long* __restrict__ packed) {
  int t = threadIdx.x + blockIdx.x * 256;
  for (int i = t; i < 128 * 512; i += 256 * 64) { h0[i] = 0.f; qh[i] = 0.f; }
  if (t < 128) packed[t] = (0x80000000ull << 32) | 0xFFFFFFFFull;  // val 0.0, idx 0
}

// ---------------------------------------------------------------------------
// Attention: one block per (b, head). q assembled from emb_q[tok] + qh + bq.
// K phase: thread -> 4 m (float4 along m), d split in half across thread groups.
// ---------------------------------------------------------------------------
__global__ __launch_bounds__(256) void attn_fused(
    const float* __restrict__ kpT, const float* __restrict__ vp,
    const float* __restrict__ emb_q, const float* __restrict__ qhp,
    const float* __restrict__ bq_p, const unsigned long long* __restrict__ packed,
    float* __restrict__ ctx, float* __restrict__ att_buf) {
  int b = blockIdx.x >> 3, hd = blockIdx.x & 7;
  __shared__ float qs[64];
  __shared__ float att[512];
  __shared__ __align__(16) float sp[128][4];
  __shared__ __align__(16) float red[16][68];
  __shared__ float rmax[2], rsum[2];
  __shared__ int tok_s;
  int t = threadIdx.x;
  if (t == 0) tok_s = (int)(0xFFFFFFFFu - (unsigned int)(packed[b] & 0xFFFFFFFFull));
  __syncthreads();
  if (t < 64) {
    qs[t] = emb_q[(size_t)tok_s * 512 + hd * 64 + t]
          + qhp[(size_t)b * 512 + hd * 64 + t] + bq_p[hd * 64 + t];
  }
  __syncthreads();
  const float* Kb = kpT + (size_t)(b * 8 + hd) * 32768;  // [64][512]
  const float* Vb = vp + (size_t)(b * 8 + hd) * 32768;   // [512][64]
  int mq = (t & 127) * 4, dh = t >> 7;
  float s0 = 0.f, s1 = 0.f, s2 = 0.f, s3 = 0.f;
  {
    const float* Kbd = Kb + (size_t)(dh * 32) * 512 + mq;
    const float* qd0 = qs + dh * 32;
    #pragma unroll 8
    for (int dd = 0; dd < 32; ++dd) {
      float4 kk = *(const float4*)(Kbd + (size_t)dd * 512);
      float qd = qd0[dd];
      s0 = fmaf(qd, kk.x, s0);
      s1 = fmaf(qd, kk.y, s1);
      s2 = fmaf(qd, kk.z, s2);
      s3 = fmaf(qd, kk.w, s3);
    }
  }
  if (dh) {
    sp[t & 127][0] = s0; sp[t & 127][1] = s1;
    sp[t & 127][2] = s2; sp[t & 127][3] = s3;
  }
  __syncthreads();
  float e0 = 0.f, e1 = 0.f, e2 = 0.f, e3 = 0.f;
  if (!dh) {
    s0 = (s0 + sp[t][0]) * 0.125f;
    s1 = (s1 + sp[t][1]) * 0.125f;
    s2 = (s2 + sp[t][2]) * 0.125f;
    s3 = (s3 + sp[t][3]) * 0.125f;
    float mx = fmaxf(fmaxf(s0, s1), fmaxf(s2, s3));
    #pragma unroll
    for (int o = 32; o > 0; o >>= 1) mx = fmaxf(mx, __shfl_xor(mx, o));
    if ((t & 63) == 0) rmax[t >> 6] = mx;
  }
  __syncthreads();
  if (!dh) {
    float mx = fmaxf(rmax[0], rmax[1]);
    e0 = expf(s0 - mx); e1 = expf(s1 - mx);
    e2 = expf(s2 - mx); e3 = expf(s3 - mx);
    float sm = e0 + e1 + e2 + e3;
    #pragma unroll
    for (int o = 32; o > 0; o >>= 1) sm += __shfl_xor(sm, o);
    if ((t & 63) == 0) rsum[t >> 6] = sm;
  }
  __syncthreads();
  if (!dh) {
    float inv = 1.f / (rsum[0] + rsum[1]);
    float4 a4;
    a4.x = e0 * inv; a4.y = e1 * inv; a4.z = e2 * inv; a4.w = e3 * inv;
    *(float4*)&att[mq] = a4;
    *(float4*)(att_buf + (size_t)(b * 8 + hd) * 512 + mq) = a4;
  }
  __syncthreads();
  // --- ctx: thread = (row-group g = t>>4, d-slice = (t&15)*4) ---
  {
    int dsl = (t & 15) * 4, g = t >> 4;
    float c0 = 0.f, c1 = 0.f, c2 = 0.f, c3 = 0.f;
    #pragma unroll 4
    for (int m = g; m < 512; m += 16) {
      float4 vv = *(const float4*)(Vb + (size_t)m * 64 + dsl);
      float am = att[m];
      c0 = fmaf(am, vv.x, c0);
      c1 = fmaf(am, vv.y, c1);
      c2 = fmaf(am, vv.z, c2);
      c3 = fmaf(am, vv.w, c3);
    }
    red[g][dsl + 0] = c0;
    red[g][dsl + 1] = c1;
    red[g][dsl + 2] = c2;
    red[g][dsl + 3] = c3;
  }
  __syncthreads();
  if (t < 64) {
    float cc = 0.f;
    #pragma unroll
    for (int g2 = 0; g2 < 16; ++g2) cc += red[g2][t];
    ctx[(size_t)b * 512 + hd * 64 + t] = cc;
  }
}

// ---------------------------------------------------------------------------
// GRU (split-K, 512 threads) + hiddens-out; blocks >=256: scores + packed reset
// grid 320: [0,256) GRU (bt16 x jt16, 32 j x 2 kh x 8 b), [256,320) scores
// ---------------------------------------------------------------------------
__global__ __launch_bounds__(512) void gru_kernel(
    const float* __restrict__ W_ih, const float* __restrict__ W_hh,
    const float* __restrict__ b_ih, const float* __restrict__ b_hh,
    const float* __restrict__ ctx, const float* __restrict__ h_prev,
    float* __restrict__ h_new, const float* __restrict__ att_buf,
    const int* __restrict__ lens, float* __restrict__ out_hid,
    float* __restrict__ out_sc, unsigned long long* __restrict__ packed,
    int step) {
  __shared__ float cs[8][512];
  __shared__ float hs[8][512];
  int bi = blockIdx.x;
  int t = threadIdx.x;
  if (bi >= 256) {
    int sb = bi - 256;  // 0..63
    if (sb == 0 && t < 128) packed[t] = 0ull;
    #pragma unroll
    for (int i = 0; i < 2; ++i) {
      int flat = sb * 1024 + i * 512 + t;
      int bb = flat >> 9, m = flat & 511;
      float sum = 0.f;
      #pragma unroll
      for (int h = 0; h < 8; ++h) sum += att_buf[(size_t)(bb * 8 + h) * 512 + m];
      out_sc[(size_t)step * 65536 + flat] = (step < lens[bb]) ? sum * 0.125f : 0.f;
    }
    return;
  }
  int bt = bi >> 4, jt = bi & 15;
  #pragma unroll
  for (int i = 0; i < 8; ++i) {
    int flat = i * 512 + t;
    int lb2 = flat >> 9, k = flat & 511;
    cs[lb2][k] = ctx[(size_t)(bt * 8 + lb2) * 512 + k];
    hs[lb2][k] = h_prev[(size_t)(bt * 8 + lb2) * 512 + k];
  }
  __syncthreads();
  int j5 = t & 31, kh = (t >> 5) & 1, lb = t >> 6;
  int j = jt * 32 + j5, b = bt * 8 + lb, k0 = kh * 256;
  const float* c = cs[lb] + k0;
  const float* hh = hs[lb] + k0;
  const float* wi0 = W_ih + (size_t)j * 512 + k0;
  const float* wi1 = W_ih + (size_t)(512 + j) * 512 + k0;
  const float* wi2 = W_ih + (size_t)(1024 + j) * 512 + k0;
  const float* wh0 = W_hh + (size_t)j * 512 + k0;
  const float* wh1 = W_hh + (size_t)(512 + j) * 512 + k0;
  const float* wh2 = W_hh + (size_t)(1024 + j) * 512 + k0;
  float air = 0.f, aiz = 0.f, ain = 0.f, ahr = 0.f, ahz = 0.f, ahn = 0.f;
  #pragma unroll 2
  for (int k = 0; k < 256; k += 4) {
    float4 wa = *(const float4*)(wi0 + k);
    float4 wb = *(const float4*)(wi1 + k);
    float4 wc = *(const float4*)(wi2 + k);
    float4 wd = *(const float4*)(wh0 + k);
    float4 we = *(const float4*)(wh1 + k);
    float4 wf = *(const float4*)(wh2 + k);
    float c0 = c[k], c1 = c[k + 1], c2 = c[k + 2], c3 = c[k + 3];
    float h0 = hh[k], h1 = hh[k + 1], h2 = hh[k + 2], h3 = hh[k + 3];
    air = fmaf(c0, wa.x, air); air = fmaf(c1, wa.y, air); air = fmaf(c2, wa.z, air); air = fmaf(c3, wa.w, air);
    aiz = fmaf(c0, wb.x, aiz); aiz = fmaf(c1, wb.y, aiz); aiz = fmaf(c2, wb.z, aiz); aiz = fmaf(c3, wb.w, aiz);
    ain = fmaf(c0, wc.x, ain); ain = fmaf(c1, wc.y, ain); ain = fmaf(c2, wc.z, ain); ain = fmaf(c3, wc.w, ain);
    ahr = fmaf(h0, wd.x, ahr); ahr = fmaf(h1, wd.y, ahr); ahr = fmaf(h2, wd.z, ahr); ahr = fmaf(h3, wd.w, ahr);
    ahz = fmaf(h0, we.x, ahz); ahz = fmaf(h1, we.y, ahz); ahz = fmaf(h2, we.z, ahz); ahz = fmaf(h3, we.w, ahz);
    ahn = fmaf(h0, wf.x, ahn); ahn = fmaf(h1, wf.y, ahn); ahn = fmaf(h2, wf.z, ahn); ahn = fmaf(h3, wf.w, ahn);
  }
  air += __shfl_xor(air, 32);
  aiz += __shfl_xor(aiz, 32);
  ain += __shfl_xor(ain, 32);
  ahr += __shfl_xor(ahr, 32);
  ahz += __shfl_xor(ahz, 32);
  ahn += __shfl_xor(ahn, 32);
  if (kh == 0) {
    air += b_ih[j]; aiz += b_ih[512 + j]; ain += b_ih[1024 + j];
    ahr += b_hh[j]; ahz += b_hh[512 + j]; ahn += b_hh[1024 + j];
    float r = 1.f / (1.f + expf(-(air + ahr)));
    float z = 1.f / (1.f + expf(-(aiz + ahz)));
    float n = tanhf(fmaf(r, ahn, ain));
    float hp = hs[lb][j];
    float hv = (1.f - z) * n + z * hp;
    h_new[(size_t)b * 512 + j] = hv;
    out_hid[(size_t)step * 65536 + (size_t)b * 512 + j] = (step < lens[b]) ? hv : 0.f;
  }
}

// ---------------------------------------------------------------------------
// Logits (split-K, 512 threads) + argmax; blocks >=256: qh = h_new @ WqhT
// grid 384: [0,256) logits (bt16 x vt16), [256,384) qh (one block per b)
// ---------------------------------------------------------------------------
__global__ __launch_bounds__(512) void logits_kernel(
    const float* __restrict__ Wfc, const float* __restrict__ bfc,
    const float* __restrict__ h_new, const int* __restrict__ lens,
    float* __restrict__ out_o, unsigned long long* __restrict__ packed,
    const float* __restrict__ WqhT, float* __restrict__ qhp, int step) {
  __shared__ float hs[8][512];
  __shared__ float hsb[512];
  __shared__ float qpart[256][2];
  int bi = blockIdx.x;
  int t = threadIdx.x;
  if (bi >= 256) {
    int bb = bi - 256;  // 0..127
    hsb[t & 511] = h_new[(size_t)bb * 512 + (t & 511)];
    __syncthreads();
    int j2 = t & 255, kh2 = t >> 8;
    const float* wt = WqhT + (size_t)(kh2 * 256) * 512 + j2 * 2;
    const float* hv2 = hsb + kh2 * 256;
    float q0 = 0.f, q1 = 0.f;
    #pragma unroll 8
    for (int k = 0; k < 256; ++k) {
      float2 w = *(const float2*)(wt + (size_t)k * 512);
      float hk = hv2[k];
      q0 = fmaf(hk, w.x, q0);
      q1 = fmaf(hk, w.y, q1);
    }
    if (kh2) { qpart[j2][0] = q0; qpart[j2][1] = q1; }
    __syncthreads();
    if (!kh2) {
      q0 += qpart[j2][0];
      q1 += qpart[j2][1];
      *(float2*)(qhp + (size_t)bb * 512 + j2 * 2) = make_float2(q0, q1);
    }
    return;
  }
  int bt = bi >> 4, vt = bi & 15;
  #pragma unroll
  for (int i = 0; i < 8; ++i) {
    int flat = i * 512 + t;
    int lb2 = flat >> 9, k = flat & 511;
    hs[lb2][k] = h_new[(size_t)(bt * 8 + lb2) * 512 + k];
  }
  __syncthreads();
  int vv = t & 31, kh = (t >> 5) & 1, lb = t >> 6;
  int b = bt * 8 + lb, k0 = kh * 256;
  int v0 = vt * 64 + vv;            // always < 1000
  int v1 = vt * 64 + 32 + vv;       // may reach 1023
  bool g1 = v1 < 1000;
  const float* a = hs[lb] + k0;
  const float* w0 = Wfc + (size_t)v0 * 512 + k0;
  const float* w1 = Wfc + (size_t)(g1 ? v1 : v0) * 512 + k0;
  float acc0 = 0.f, acc1 = 0.f;
  #pragma unroll 2
  for (int k = 0; k < 256; k += 4) {
    float4 wA = *(const float4*)(w0 + k);
    float4 wB = *(const float4*)(w1 + k);
    float a0 = a[k], a1 = a[k + 1], a2 = a[k + 2], a3 = a[k + 3];
    acc0 = fmaf(a0, wA.x, acc0); acc0 = fmaf(a1, wA.y, acc0);
    acc0 = fmaf(a2, wA.z, acc0); acc0 = fmaf(a3, wA.w, acc0);
    acc1 = fmaf(a0, wB.x, acc1); acc1 = fmaf(a1, wB.y, acc1);
    acc1 = fmaf(a2, wB.z, acc1); acc1 = fmaf(a3, wB.w, acc1);
  }
  acc0 += __shfl_xor(acc0, 32);
  acc1 += __shfl_xor(acc1, 32);
  float bestv = -1e30f;
  int besti = 0;
  if (kh == 0) {
    int run = step < lens[b];
    size_t ofs = (size_t)step * 128000 + (size_t)b * 1000;
    float f0 = acc0 + bfc[v0];
    out_o[ofs + v0] = run ? f0 : 0.f;
    bestv = f0; besti = v0;
    if (g1) {
      float f1 = acc1 + bfc[v1];
      out_o[ofs + v1] = run ? f1 : 0.f;
      if (f1 > bestv) { bestv = f1; besti = v1; }
    }
  }
  #pragma unroll
  for (int o = 16; o > 0; o >>= 1) {
    float ov = __shfl_xor(bestv, o);
    int oi = __shfl_xor(besti, o);
    if (ov > bestv || (ov == bestv && oi < besti)) { bestv = ov; besti = oi; }
  }
  if ((t & 63) == 0) {
    unsigned int fb = __float_as_uint(bestv);
    fb = (fb & 0x80000000u) ? ~fb : (fb | 0x80000000u);
    unsigned long long key =
        ((unsigned long long)fb << 32) | (unsigned long long)(0xFFFFFFFFu - (unsigned int)besti);
    atomicMax(packed + b, key);
  }
}

// ---------------------------------------------------------------------------
extern "C" void kernel_launch(void* const* d_in, const int* in_sizes, int n_in,
                              void* d_out, int out_size, void* d_ws, size_t ws_size,
                              hipStream_t stream) {
  const float* memory = (const float*)d_in[0];
  const float* emb    = (const float*)d_in[1];
  const float* Wq     = (const float*)d_in[2];
  const float* bq     = (const float*)d_in[3];
  const float* Wk     = (const float*)d_in[4];
  const float* bk     = (const float*)d_in[5];
  const float* Wv     = (const float*)d_in[6];
  const float* bv     = (const float*)d_in[7];
  const float* W_ih   = (const float*)d_in[8];
  const float* W_hh   = (const float*)d_in[9];
  const float* b_ih   = (const float*)d_in[10];
  const float* b_hh   = (const float*)d_in[11];
  const float* Wfc    = (const float*)d_in[12];
  const float* bfc    = (const float*)d_in[13];
  const int* lens     = (const int*)d_in[14];

  float* ws = (float*)d_ws;
  float* kpT     = ws;                    // 33,554,432 f  [b][h][d][m]
  float* vp      = kpT + 33554432;        // 33,554,432 f  [b][h][m][d]
  float* ctx     = vp + 33554432;         // 65,536 f
  float* h0      = ctx + 65536;           // 65,536 f
  float* h1      = h0 + 65536;            // 65,536 f
  float* att_buf = h1 + 65536;            // 524,288 f
  float* qh      = att_buf + 524288;      // 65,536 f
  float* emb_q   = qh + 65536;            // 512,000 f  [v][j]
  float* WqhT    = emb_q + 512000;        // 262,144 f  [k][j]
  unsigned long long* packed = (unsigned long long*)(WqhT + 262144);  // 128 u64

  float* out   = (float*)d_out;
  float* out_o = out;                  // 160*128*1000
  float* out_h = out + 20480000;       // 160*128*512
  float* out_s = out_h + 10485760;     // 160*128*512

  kv_projT<<<8192, 256, 0, stream>>>(memory, Wk, bk, kpT);
  kv_proj<<<8192, 256, 0, stream>>>(memory, Wv, bv, vp);
  embq_proj<<<128, 256, 0, stream>>>(emb, Wq, emb_q);
  wqh_transpose<<<1024, 256, 0, stream>>>(Wq, WqhT);
  init_kernel<<<64, 256, 0, stream>>>(h0, qh, packed);

  for (int t = 0; t < 160; ++t) {
    float* hp = (t & 1) ? h1 : h0;
    float* hn = (t & 1) ? h0 : h1;
    attn_fused<<<1024, 256, 0, stream>>>(kpT, vp, emb_q, qh, bq, packed, ctx, att_buf);
    gru_kernel<<<320, 512, 0, stream>>>(W_ih, W_hh, b_ih, b_hh, ctx, hp, hn,
                                        att_buf, lens, out_h, out_s, packed, t);
    logits_kernel<<<384, 512, 0, stream>>>(Wfc, bfc, hn, lens, out_o, packed,
                                           WqhT, qh, t);
  }
}